// Round 7
// baseline (75.669 us; speedup 1.0000x reference)
//
#include <hip/hip_runtime.h>

#define M_ 256
#define K_ 8192
#define N_ 8192

typedef int v4i __attribute__((ext_vector_type(4)));
typedef int v16i __attribute__((ext_vector_type(16)));

// ---------------- kernel 1: per-token int8 quantization ----------------
// Writes xq in MFMA-A-fragment-tiled layout (bijective byte map, 2 MB):
//   (m,k) -> addr = (mt<<18) + (chunk<<13) + (ks<<10) + (lane<<4) + b
//   mt=m>>5, chunk=k>>8, ks=(k>>5)&7, lane=(m&31)+32*((k>>4)&1), b=k&15
__global__ __launch_bounds__(256) void awq_quant(const float* __restrict__ x,
                                                 signed char* __restrict__ xqt,
                                                 float* __restrict__ scales) {
    const int m = blockIdx.x;
    const int t = threadIdx.x;
    const float4* xrow = (const float4*)(x + (size_t)m * K_);
    float4 v[8];
    float mx = 0.0f;
#pragma unroll
    for (int j = 0; j < 8; ++j) {
        v[j] = xrow[j * 256 + t];
        mx = fmaxf(mx, fmaxf(fmaxf(fabsf(v[j].x), fabsf(v[j].y)),
                             fmaxf(fabsf(v[j].z), fabsf(v[j].w))));
    }
#pragma unroll
    for (int off = 32; off > 0; off >>= 1) mx = fmaxf(mx, __shfl_xor(mx, off, 64));
    __shared__ float red[4];
    if ((t & 63) == 0) red[t >> 6] = mx;
    __syncthreads();
    mx = fmaxf(fmaxf(red[0], red[1]), fmaxf(red[2], red[3]));
    const float scale = fmaxf(mx / 127.0f, 1e-8f);

    char* base = (char*)xqt + ((size_t)(m >> 5) << 18);
    const int ml = m & 31;
#pragma unroll
    for (int j = 0; j < 8; ++j) {
        const int q0 = (int)fminf(fmaxf(rintf(v[j].x / scale), -127.0f), 127.0f);
        const int q1 = (int)fminf(fmaxf(rintf(v[j].y / scale), -127.0f), 127.0f);
        const int q2 = (int)fminf(fmaxf(rintf(v[j].z / scale), -127.0f), 127.0f);
        const int q3 = (int)fminf(fmaxf(rintf(v[j].w / scale), -127.0f), 127.0f);
        const int packed = (q0 & 255) | ((q1 & 255) << 8) | ((q2 & 255) << 16) | ((q3 & 255) << 24);
        const int k0 = 4 * (j * 256 + t);
        const int addr = ((k0 >> 8) << 13) + (((k0 >> 5) & 7) << 10) +
                         ((ml + (((k0 >> 4) & 1) << 5)) << 4) + (k0 & 15);
        *(int*)(base + addr) = packed;
    }
    if (t == 0) scales[m] = scale;
}

// ---------------- kernel 2: int8 GEMM + dequant epilogue ----------------
// grid = 256 blocks (1/CU), 512 thr = 8 waves, one 32x32 m-tile per wave.
// 16 phases, each covering a PAIR of 256-k chunks (512 k-values): halves
// barrier count vs 32-phase version to amortize per-phase fixed cost
// (lgkm drain + 8-wave barrier skew + latency tail). One raw barrier per
// phase, lgkmcnt-only drain, never vmcnt(0): qw loads stay in flight
// across barriers. LDS: 2 x 32 rows x 528B (512B data + 16 pad).

__device__ __forceinline__ void stage_pair(char* btn, int bwo, const int4* w) {
#pragma unroll
    for (int c = 0; c < 2; ++c) {
        const int* p0 = (const int*)&w[c * 4 + 0];
        const int* p1 = (const int*)&w[c * 4 + 1];
        const int* p2 = (const int*)&w[c * 4 + 2];
        const int* p3 = (const int*)&w[c * 4 + 3];
#pragma unroll
        for (int j = 0; j < 4; ++j) {
            const unsigned u = __builtin_amdgcn_perm((unsigned)p1[j], (unsigned)p0[j], 0x00000400u);
            const unsigned v = __builtin_amdgcn_perm((unsigned)p3[j], (unsigned)p2[j], 0x00000400u);
            const unsigned o = __builtin_amdgcn_perm(v, u, 0x05040100u);
            *(unsigned*)(btn + bwo + c * 256 + j * 528) = o;
        }
    }
}

__global__ __launch_bounds__(512, 2) void awq_gemm(const signed char* __restrict__ xqt,
                                                   const float* __restrict__ scales,
                                                   const int* __restrict__ qw,
                                                   const float* __restrict__ wscale,
                                                   const float* __restrict__ bias,
                                                   float* __restrict__ out) {
    __shared__ __align__(16) char btile[2][32 * 528];
    const int t = threadIdx.x;
    const int lane = t & 63;
    const int wave = t >> 6;
    const int n0 = blockIdx.x * 32;

    const int sa = t & 7;                  // n-group: cols n0 + 4*sa + j
    const int sr = t >> 3;                 // 0..63: k rows 4*sr + i (per chunk)
    const int* qbase = qw + (size_t)(4 * sr) * N_ + n0 + 4 * sa;

    // tiled A base: wave's m-tile (256KB each), this lane's 16B slot
    const signed char* xqb = xqt + ((size_t)wave << 18) + lane * 16;

    const int bro = (lane & 31) * 528 + (lane >> 5) * 16;
    const int bwo = (4 * sa) * 528 + 4 * sr;

    v16i acc = {};
    v4i aF[16];
    int4 sA[8], sB[8];

    // pair p covers chunks 2p, 2p+1 (k rows [512p, 512p+512))
    auto loadq = [&](int4* dst, int pair) {
        const int4* q = (const int4*)(qbase + (size_t)pair * 512 * N_);
#pragma unroll
        for (int c = 0; c < 2; ++c)
#pragma unroll
            for (int i = 0; i < 4; ++i)
                dst[c * 4 + i] = q[(size_t)(256 * c + i) * (N_ / 4)];
    };

    // prologue: sA <- pair0, sB <- pair1; aF <- pair0; stage pair0 -> buf0
    loadq(sA, 0);
    loadq(sB, 1);
#pragma unroll
    for (int f = 0; f < 16; ++f)
        aF[f] = *(const v4i*)(xqb + (f >> 3) * 8192 + (f & 7) * 1024);
    stage_pair(&btile[0][0], bwo, sA);
    asm volatile("s_waitcnt lgkmcnt(0)" ::: "memory");
    __builtin_amdgcn_s_barrier();
    __builtin_amdgcn_sched_barrier(0);

    for (int p = 0; p < 16; p += 2) {
        {   // even phase p: compute pair p (buf0); loadq sA <- pair p+2;
            // refill aF <- pair p+1; stage pair p+1 (sB) -> buf1
            const int pn = (p + 2 < 16) ? p + 2 : 15;
            loadq(sA, pn);
            __builtin_amdgcn_sched_barrier(0);
            const int ra = (p + 1 < 16) ? p + 1 : 15;
            const char* btc = &btile[0][0];
#pragma unroll
            for (int f = 0; f < 16; ++f) {
                const v4i bf = *(const v4i*)(btc + bro + (f >> 3) * 256 + (f & 7) * 32);
                acc = __builtin_amdgcn_mfma_i32_32x32x32_i8(aF[f], bf, acc, 0, 0, 0);
                aF[f] = *(const v4i*)(xqb + (size_t)ra * 16384 + (f >> 3) * 8192 + (f & 7) * 1024);
            }
            stage_pair(&btile[1][0], bwo, sB);
            asm volatile("s_waitcnt lgkmcnt(0)" ::: "memory");
            __builtin_amdgcn_s_barrier();
            __builtin_amdgcn_sched_barrier(0);
        }
        {   // odd phase p+1: compute pair p+1 (buf1); loadq sB <- pair p+3;
            // refill aF <- pair p+2; stage pair p+2 (sA) -> buf0
            const int pn = (p + 3 < 16) ? p + 3 : 15;
            loadq(sB, pn);
            __builtin_amdgcn_sched_barrier(0);
            const int ra = (p + 2 < 16) ? p + 2 : 15;
            const char* btc = &btile[1][0];
#pragma unroll
            for (int f = 0; f < 16; ++f) {
                const v4i bf = *(const v4i*)(btc + bro + (f >> 3) * 256 + (f & 7) * 32);
                acc = __builtin_amdgcn_mfma_i32_32x32x32_i8(aF[f], bf, acc, 0, 0, 0);
                aF[f] = *(const v4i*)(xqb + (size_t)ra * 16384 + (f >> 3) * 8192 + (f & 7) * 1024);
            }
            stage_pair(&btile[0][0], bwo, sA);
            asm volatile("s_waitcnt lgkmcnt(0)" ::: "memory");
            __builtin_amdgcn_s_barrier();
            __builtin_amdgcn_sched_barrier(0);
        }
    }

    // epilogue: dequant. C/D layout: col=lane&31, row=(g&3)+8*(g>>2)+4*(lane>>5)
    const int n = n0 + (lane & 31);
    const float wn = wscale[n];
    const float bn = bias[n];
    const int mb = wave * 32 + 4 * (lane >> 5);
#pragma unroll
    for (int g = 0; g < 16; ++g) {
        const int m = mb + (g & 3) + 8 * (g >> 2);
        out[(size_t)m * N_ + n] = ((float)acc[g] * scales[m]) * wn + bn;
    }
}

extern "C" void kernel_launch(void* const* d_in, const int* in_sizes, int n_in,
                              void* d_out, int out_size, void* d_ws, size_t ws_size,
                              hipStream_t stream) {
    const float* x    = (const float*)d_in[0];
    const int*   qw   = (const int*)d_in[1];
    const float* wsc  = (const float*)d_in[2];
    const float* bias = (const float*)d_in[3];
    float* out = (float*)d_out;

    signed char* xqbuf  = (signed char*)d_ws;                      // 2 MB, tiled
    float*       scales = (float*)((char*)d_ws + (size_t)M_ * K_); // 1 KB

    awq_quant<<<M_, 256, 0, stream>>>(x, xqbuf, scales);
    awq_gemm<<<N_ / 32, 512, 0, stream>>>(xqbuf, scales, qw, wsc, bias, out);
}

// Round 8
// 67.601 us; speedup vs baseline: 1.1193x; 1.1193x over previous
//
#include <hip/hip_runtime.h>

#define M_ 256
#define K_ 8192
#define N_ 8192

typedef int v4i __attribute__((ext_vector_type(4)));
typedef int v16i __attribute__((ext_vector_type(16)));

// ---------------- kernel 1: per-token int8 quantization ----------------
// Writes xq in MFMA-A-fragment-tiled layout (bijective byte map, 2 MB):
//   (m,k) -> addr = (mt<<18) + (chunk<<13) + (ks<<10) + (lane<<4) + b
//   mt=m>>5, chunk=k>>8, ks=(k>>5)&7, lane=(m&31)+32*((k>>4)&1), b=k&15
__global__ __launch_bounds__(256) void awq_quant(const float* __restrict__ x,
                                                 signed char* __restrict__ xqt,
                                                 float* __restrict__ scales) {
    const int m = blockIdx.x;
    const int t = threadIdx.x;
    const float4* xrow = (const float4*)(x + (size_t)m * K_);
    float4 v[8];
    float mx = 0.0f;
#pragma unroll
    for (int j = 0; j < 8; ++j) {
        v[j] = xrow[j * 256 + t];
        mx = fmaxf(mx, fmaxf(fmaxf(fabsf(v[j].x), fabsf(v[j].y)),
                             fmaxf(fabsf(v[j].z), fabsf(v[j].w))));
    }
#pragma unroll
    for (int off = 32; off > 0; off >>= 1) mx = fmaxf(mx, __shfl_xor(mx, off, 64));
    __shared__ float red[4];
    if ((t & 63) == 0) red[t >> 6] = mx;
    __syncthreads();
    mx = fmaxf(fmaxf(red[0], red[1]), fmaxf(red[2], red[3]));
    const float scale = fmaxf(mx / 127.0f, 1e-8f);

    char* base = (char*)xqt + ((size_t)(m >> 5) << 18);
    const int ml = m & 31;
#pragma unroll
    for (int j = 0; j < 8; ++j) {
        const int q0 = (int)fminf(fmaxf(rintf(v[j].x / scale), -127.0f), 127.0f);
        const int q1 = (int)fminf(fmaxf(rintf(v[j].y / scale), -127.0f), 127.0f);
        const int q2 = (int)fminf(fmaxf(rintf(v[j].z / scale), -127.0f), 127.0f);
        const int q3 = (int)fminf(fmaxf(rintf(v[j].w / scale), -127.0f), 127.0f);
        const int packed = (q0 & 255) | ((q1 & 255) << 8) | ((q2 & 255) << 16) | ((q3 & 255) << 24);
        const int k0 = 4 * (j * 256 + t);
        const int addr = ((k0 >> 8) << 13) + (((k0 >> 5) & 7) << 10) +
                         ((ml + (((k0 >> 4) & 1) << 5)) << 4) + (k0 & 15);
        *(int*)(base + addr) = packed;
    }
    if (t == 0) scales[m] = scale;
}

// ---------------- kernel 2: int8 GEMM + dequant epilogue ----------------
// grid = 256 blocks (1/CU), 512 thr = 8 waves, one 32x32 m-tile per wave.
// 32 phases. DISTANCE-4 monotone prefetch: 4 qw reg-sets (s0..s3) and 4
// A-frag sets (a0..a3), both loaded 4 phases ahead, issued in consumption
// order so in-order vmcnt retirement never couples a fast L2 refill to a
// younger HBM load. Waits only touch loads ~3-4 phases old (slack > loaded
// HBM round-trip) -> throttled by HBM service rate only. One raw barrier
// per phase, lgkmcnt-only drain, never vmcnt(0).

__device__ __forceinline__ void stage_b(char* btn, int bwo,
                                        const int4& w0, const int4& w1,
                                        const int4& w2, const int4& w3) {
    const int* p0 = (const int*)&w0;
    const int* p1 = (const int*)&w1;
    const int* p2 = (const int*)&w2;
    const int* p3 = (const int*)&w3;
#pragma unroll
    for (int j = 0; j < 4; ++j) {
        const unsigned u = __builtin_amdgcn_perm((unsigned)p1[j], (unsigned)p0[j], 0x00000400u);
        const unsigned w = __builtin_amdgcn_perm((unsigned)p3[j], (unsigned)p2[j], 0x00000400u);
        const unsigned o = __builtin_amdgcn_perm(w, u, 0x05040100u);
        *(unsigned*)(btn + bwo + j * 272) = o;
    }
}

__global__ __launch_bounds__(512, 2) void awq_gemm(const signed char* __restrict__ xqt,
                                                   const float* __restrict__ scales,
                                                   const int* __restrict__ qw,
                                                   const float* __restrict__ wscale,
                                                   const float* __restrict__ bias,
                                                   float* __restrict__ out) {
    __shared__ __align__(16) char btile[2][32 * 272];
    const int t = threadIdx.x;
    const int lane = t & 63;
    const int wave = t >> 6;
    const int n0 = blockIdx.x * 32;

    const int sa = t & 7;                  // n-group
    const int sr = t >> 3;                 // k-row group (0..63)
    const int* qbase = qw + (size_t)(4 * sr) * N_ + n0 + 4 * sa;

    // tiled A base: wave's m-tile (256KB each), this lane's 16B slot
    const signed char* xqb = xqt + ((size_t)wave << 18) + lane * 16;

    const int bro = (lane & 31) * 272 + (lane >> 5) * 16;
    const int bwo = (4 * sa) * 272 + 4 * sr;

    v16i acc = {};
    v4i a0[8], a1[8], a2[8], a3[8];
    int4 s0[4], s1[4], s2[4], s3[4];

    auto loadq = [&](int4* dst, int chunk) {
        const int4* q = (const int4*)(qbase + (size_t)chunk * 256 * N_);
        dst[0] = q[0];
        dst[1] = q[N_ / 4];
        dst[2] = q[2 * (N_ / 4)];
        dst[3] = q[3 * (N_ / 4)];
    };
    auto loada = [&](v4i* a, int chunk) {
#pragma unroll
        for (int f = 0; f < 8; ++f)
            a[f] = *(const v4i*)(xqb + (size_t)chunk * 8192 + f * 1024);
    };

    // prologue: monotone stream s0,a0,s1,a1,s2,a2,s3,a3 <- chunks 0..3
    loadq(s0, 0); loada(a0, 0);
    loadq(s1, 1); loada(a1, 1);
    loadq(s2, 2); loada(a2, 2);
    loadq(s3, 3); loada(a3, 3);
    stage_b(&btile[0][0], bwo, s0[0], s0[1], s0[2], s0[3]);
    asm volatile("s_waitcnt lgkmcnt(0)" ::: "memory");
    __builtin_amdgcn_s_barrier();
    __builtin_amdgcn_sched_barrier(0);

#define PHASE(P_, AREG, SCUR, SNEXT, BUFC, BUFN)                                    \
    {                                                                               \
        const int cf = (P_) + 4;                                                    \
        if (cf < 32) loadq(SCUR, cf);                                               \
        const char* btc = &btile[BUFC][0];                                          \
        _Pragma("unroll")                                                           \
        for (int f = 0; f < 8; ++f) {                                               \
            const v4i bf = *(const v4i*)(btc + bro + f * 32);                       \
            acc = __builtin_amdgcn_mfma_i32_32x32x32_i8(AREG[f], bf, acc, 0, 0, 0); \
        }                                                                           \
        if (cf < 32) loada(AREG, cf);                                               \
        stage_b(&btile[BUFN][0], bwo, SNEXT[0], SNEXT[1], SNEXT[2], SNEXT[3]);      \
        asm volatile("s_waitcnt lgkmcnt(0)" ::: "memory");                          \
        __builtin_amdgcn_s_barrier();                                               \
        __builtin_amdgcn_sched_barrier(0);                                          \
    }

    for (int sc = 0; sc < 32; sc += 4) {
        PHASE(sc + 0, a0, s0, s1, 0, 1)
        PHASE(sc + 1, a1, s1, s2, 1, 0)
        PHASE(sc + 2, a2, s2, s3, 0, 1)
        PHASE(sc + 3, a3, s3, s0, 1, 0)
    }
#undef PHASE

    // epilogue: dequant. C/D layout: col=lane&31, row=(g&3)+8*(g>>2)+4*(lane>>5)
    const int n = n0 + (lane & 31);
    const float wn = wscale[n];
    const float bn = bias[n];
    const int mb = wave * 32 + 4 * (lane >> 5);
#pragma unroll
    for (int g = 0; g < 16; ++g) {
        const int m = mb + (g & 3) + 8 * (g >> 2);
        out[(size_t)m * N_ + n] = ((float)acc[g] * scales[m]) * wn + bn;
    }
}

extern "C" void kernel_launch(void* const* d_in, const int* in_sizes, int n_in,
                              void* d_out, int out_size, void* d_ws, size_t ws_size,
                              hipStream_t stream) {
    const float* x    = (const float*)d_in[0];
    const int*   qw   = (const int*)d_in[1];
    const float* wsc  = (const float*)d_in[2];
    const float* bias = (const float*)d_in[3];
    float* out = (float*)d_out;

    signed char* xqbuf  = (signed char*)d_ws;                      // 2 MB, tiled
    float*       scales = (float*)((char*)d_ws + (size_t)M_ * K_); // 1 KB

    awq_quant<<<M_, 256, 0, stream>>>(x, xqbuf, scales);
    awq_gemm<<<N_ / 32, 512, 0, stream>>>(xqbuf, scales, qw, wsc, bias, out);
}